// Round 3
// baseline (486.463 us; speedup 1.0000x reference)
//
#include <hip/hip_runtime.h>

#define V 4096
#define F 64
#define H 16
#define GSZ 1024
#define EPS 1e-8f
#define SLOPE 0.2f
#define NGRP 4            // groups of 4 consecutive columns -> 16 cols/thread

typedef float f4 __attribute__((ext_vector_type(4)));

// ---------------- Kernel A: per-node precompute + packing ----------------
// nd[i*8 + 0..7] = {px, py, vx, vy, dirx, diry, lj, bitcast(gc)}
__global__ __launch_bounds__(256) void prep_kernel(
    const float* __restrict__ feat,      // [V,F]
    const float* __restrict__ pos,       // [V,2]
    const float* __restrict__ vel,       // [V,2]
    const int*   __restrict__ types,     // [V]
    const int*   __restrict__ nped,      // [1]
    const float* __restrict__ Wp,        // [F,H]
    const float* __restrict__ wscore,    // [2H+4]
    float* __restrict__ h,               // [V,H]
    float* __restrict__ li,              // [V]
    float* __restrict__ nd)              // [V,8]
{
    int i = blockIdx.x * blockDim.x + threadIdx.x;
    if (i >= V) return;

    float acc[H];
#pragma unroll
    for (int c = 0; c < H; ++c) acc[c] = 0.f;
    for (int f = 0; f < F; ++f) {
        float x = feat[i * F + f];
#pragma unroll
        for (int c = 0; c < H; ++c) acc[c] += x * Wp[f * H + c];
    }
    float sli = 0.f, slj = 0.f;
#pragma unroll
    for (int c = 0; c < H; ++c) {
        h[i * H + c] = acc[c];
        sli += acc[c] * wscore[c];
        slj += acc[c] * wscore[H + c];
    }
    li[i] = sli;

    float vx = vel[i * 2], vy = vel[i * 2 + 1];
    float inv = 1.f / (sqrtf(vx * vx + vy * vy) + EPS);
    int P = nped[0];
    int g = i - P;
    int gc = (types[i] == 1 && g >= 0 && g < GSZ) ? g : -1;

    nd[i * 8 + 0] = pos[i * 2];
    nd[i * 8 + 1] = pos[i * 2 + 1];
    nd[i * 8 + 2] = vx;
    nd[i * 8 + 3] = vy;
    nd[i * 8 + 4] = vx * inv;
    nd[i * 8 + 5] = vy * inv;
    nd[i * 8 + 6] = slj;
    nd[i * 8 + 7] = __int_as_float(gc);
}

// ---------------- Kernel B: one block per row ----------------
__global__ __launch_bounds__(256, 4) void row_kernel(
    const float* __restrict__ adj,       // [V,V]
    const float* __restrict__ conflict,  // [G,G]
    const float* __restrict__ wscore,    // [2H+4]
    const float* __restrict__ h,         // [V,H]
    const float* __restrict__ li,        // [V]
    const float* __restrict__ nd,        // [V,8]
    float* __restrict__ out_att,         // [V,H]
    float* __restrict__ out_attn,        // [V,V]
    float* __restrict__ out_phi)         // [V,V,4]
{
    const int i   = blockIdx.x;
    const int tid = threadIdx.x;

    __shared__ float red[8];
    __shared__ float atile[4 * H];

    const f4* nd4 = (const f4*)nd;
    const f4 ra = nd4[2 * i];
    const f4 rb = nd4[2 * i + 1];
    const float pix = ra.x, piy = ra.y, vix = ra.z, viy = ra.w;
    const float dix = rb.x, diy = rb.y;
    const int   gi  = __float_as_int(rb.w);
    const float li_i = li[i];
    const float w0 = wscore[2 * H + 0];
    const float w1 = wscore[2 * H + 1];
    const float w2 = wscore[2 * H + 2];
    const float w3 = wscore[2 * H + 3];

    const f4* adjrow4 = (const f4*)(adj + (size_t)i * V);
    f4*       phirow  = (f4*)out_phi + (size_t)i * V;
    f4*       attnrow4 = (f4*)(out_attn + (size_t)i * V);

    // ---- pass 1: phi + ea = a*exp(leaky(logit)) (max-shift-invariant), s, t ----
    float ea[NGRP * 4];
    float s0 = 0.f, s1 = 0.f, t0 = 0.f, t1 = 0.f;
#pragma unroll
    for (int k = 0; k < NGRP; ++k) {
        const int g4 = tid + k * 256;     // f4-granule index
        const int jb = g4 * 4;            // base column (4 consecutive)
        f4 a4 = __builtin_nontemporal_load(adjrow4 + g4);
#pragma unroll
        for (int c = 0; c < 4; ++c) {
            const int j = jb + c;
            f4 na = nd4[2 * j];
            f4 nb = nd4[2 * j + 1];
            float dx = pix - na.x, dy = piy - na.y;
            float dist = sqrtf(dx * dx + dy * dy);
            float dvx = vix - na.z, dvy = viy - na.w;
            float vdiff = sqrtf(dvx * dvx + dvy * dvy);
            float al = fminf(1.f, fmaxf(-1.f, dix * nb.x + diy * nb.y));
            int gj = __float_as_int(nb.w);
            float conf = (gi >= 0 && gj >= 0) ? conflict[(size_t)gi * GSZ + gj] : 0.f;

            f4 ph;
            ph.x = dist; ph.y = vdiff; ph.z = al; ph.w = conf;
            __builtin_nontemporal_store(ph, phirow + j);

            float lg = li_i + nb.z + dist * w0 + vdiff * w1 + al * w2 + conf * w3;
            lg = (lg >= 0.f) ? lg : SLOPE * lg;
            float a = a4[c];
            float e = (a > 0.f) ? __expf(fminf(lg, 80.f)) : 0.f;
            float eav = e * a;
            ea[k * 4 + c] = eav;
            if (c & 1) { s1 += e; t1 += eav; } else { s0 += e; t0 += eav; }
        }
    }
    float s = s0 + s1, t = t0 + t1;
#pragma unroll
    for (int off = 32; off; off >>= 1) {
        s += __shfl_xor(s, off);
        t += __shfl_xor(t, off);
    }
    if ((tid & 63) == 0) { red[tid >> 6] = s; red[4 + (tid >> 6)] = t; }
    __syncthreads();
    s = red[0] + red[1] + red[2] + red[3];
    t = red[4] + red[5] + red[6] + red[7];
    const float denom = t + EPS * s;
    const float dinv  = (denom > 0.f) ? 1.f / denom : 0.f;

    // ---- pass 2: attn row (f4 stores) + attended accumulation ----
    float acc[H];
#pragma unroll
    for (int c = 0; c < H; ++c) acc[c] = 0.f;
    const f4* h4 = (const f4*)h;
#pragma unroll
    for (int k = 0; k < NGRP; ++k) {
        const int g4 = tid + k * 256;
        const int jb = g4 * 4;
        f4 w4;
#pragma unroll
        for (int c = 0; c < 4; ++c) w4[c] = ea[k * 4 + c] * dinv;
        __builtin_nontemporal_store(w4, attnrow4 + g4);
#pragma unroll
        for (int c = 0; c < 4; ++c) {
            const int j = jb + c;
            float w = w4[c];
#pragma unroll
            for (int c4 = 0; c4 < H / 4; ++c4) {
                f4 hv = h4[j * (H / 4) + c4];
                acc[c4 * 4 + 0] += w * hv.x;
                acc[c4 * 4 + 1] += w * hv.y;
                acc[c4 * 4 + 2] += w * hv.z;
                acc[c4 * 4 + 3] += w * hv.w;
            }
        }
    }
#pragma unroll
    for (int c = 0; c < H; ++c)
#pragma unroll
        for (int off = 32; off; off >>= 1) acc[c] += __shfl_xor(acc[c], off);

    if ((tid & 63) == 0) {
        int wv = tid >> 6;
#pragma unroll
        for (int c = 0; c < H; ++c) atile[wv * H + c] = acc[c];
    }
    __syncthreads();
    if (tid < H) {
        out_att[(size_t)i * H + tid] =
            atile[tid] + atile[H + tid] + atile[2 * H + tid] + atile[3 * H + tid];
    }
}

extern "C" void kernel_launch(void* const* d_in, const int* in_sizes, int n_in,
                              void* d_out, int out_size, void* d_ws, size_t ws_size,
                              hipStream_t stream) {
    const float* feat     = (const float*)d_in[0];
    const float* adj      = (const float*)d_in[1];
    const float* pos      = (const float*)d_in[2];
    const float* vel      = (const float*)d_in[3];
    const int*   types    = (const int*)  d_in[4];
    const int*   nped     = (const int*)  d_in[5];
    const float* conflict = (const float*)d_in[6];
    const float* Wp       = (const float*)d_in[7];
    const float* wscore   = (const float*)d_in[8];

    float* out = (float*)d_out;
    float* out_att  = out;                                   // [V,H]
    float* out_attn = out + (size_t)V * H;                   // [V,V]
    float* out_phi  = out + (size_t)V * H + (size_t)V * V;   // [V,V,4]

    float* ws = (float*)d_ws;
    float* h  = ws;                        // V*H
    float* li = h + (size_t)V * H;         // V
    float* nd = li + V;                    // V*8

    prep_kernel<<<dim3(V / 256), dim3(256), 0, stream>>>(
        feat, pos, vel, types, nped, Wp, wscore, h, li, nd);

    row_kernel<<<dim3(V), dim3(256), 0, stream>>>(
        adj, conflict, wscore, h, li, nd, out_att, out_attn, out_phi);
}

// Round 4
// 240.244 us; speedup vs baseline: 2.0249x; 2.0249x over previous
//
#include <hip/hip_runtime.h>

#define V 4096
#define F 64
#define H 16
#define GSZ 1024
#define EPS 1e-8f
#define SLOPE 0.2f
#define NITER (V / 256)   // 16 columns per thread

typedef float f4 __attribute__((ext_vector_type(4)));

// ---------------- Kernel A: per-node precompute + packing ----------------
// nd[i*8 + 0..7] = {px, py, vx, vy, dirx, diry, lj, bitcast(gc)}
__global__ __launch_bounds__(256) void prep_kernel(
    const float* __restrict__ feat,      // [V,F]
    const float* __restrict__ pos,       // [V,2]
    const float* __restrict__ vel,       // [V,2]
    const int*   __restrict__ types,     // [V]
    const int*   __restrict__ nped,      // [1]
    const float* __restrict__ Wp,        // [F,H]
    const float* __restrict__ wscore,    // [2H+4]
    float* __restrict__ h,               // [V,H]
    float* __restrict__ li,              // [V]
    float* __restrict__ nd)              // [V,8]
{
    int i = blockIdx.x * blockDim.x + threadIdx.x;
    if (i >= V) return;

    float acc[H];
#pragma unroll
    for (int c = 0; c < H; ++c) acc[c] = 0.f;
    for (int f = 0; f < F; ++f) {
        float x = feat[i * F + f];
#pragma unroll
        for (int c = 0; c < H; ++c) acc[c] += x * Wp[f * H + c];
    }
    float sli = 0.f, slj = 0.f;
#pragma unroll
    for (int c = 0; c < H; ++c) {
        h[i * H + c] = acc[c];
        sli += acc[c] * wscore[c];
        slj += acc[c] * wscore[H + c];
    }
    li[i] = sli;

    float vx = vel[i * 2], vy = vel[i * 2 + 1];
    float inv = 1.f / (sqrtf(vx * vx + vy * vy) + EPS);
    int P = nped[0];
    int g = i - P;
    int gc = (types[i] == 1 && g >= 0 && g < GSZ) ? g : -1;

    nd[i * 8 + 0] = pos[i * 2];
    nd[i * 8 + 1] = pos[i * 2 + 1];
    nd[i * 8 + 2] = vx;
    nd[i * 8 + 3] = vy;
    nd[i * 8 + 4] = vx * inv;
    nd[i * 8 + 5] = vy * inv;
    nd[i * 8 + 6] = slj;
    nd[i * 8 + 7] = __int_as_float(gc);
}

// ---------------- Kernel B: one block per row, R2 layout, 8 blocks/CU ----
__global__ __launch_bounds__(256, 8) void row_kernel(
    const float* __restrict__ adj,       // [V,V]
    const float* __restrict__ conflict,  // [G,G]
    const float* __restrict__ wscore,    // [2H+4]
    const float* __restrict__ h,         // [V,H]
    const float* __restrict__ li,        // [V]
    const float* __restrict__ nd,        // [V,8]
    float* __restrict__ out_att,         // [V,H]
    float* __restrict__ out_attn,        // [V,V]
    float* __restrict__ out_phi)         // [V,V,4]
{
    const int i   = blockIdx.x;
    const int tid = threadIdx.x;

    __shared__ float red[8];
    __shared__ float atile[4 * H];

    const f4* nd4 = (const f4*)nd;
    const f4 ra = nd4[2 * i];
    const f4 rb = nd4[2 * i + 1];
    const float pix = ra.x, piy = ra.y, vix = ra.z, viy = ra.w;
    const float dix = rb.x, diy = rb.y;
    const int   gi  = __float_as_int(rb.w);
    const float li_i = li[i];
    const float w0 = wscore[2 * H + 0];
    const float w1 = wscore[2 * H + 1];
    const float w2 = wscore[2 * H + 2];
    const float w3 = wscore[2 * H + 3];

    const float* adjrow  = adj + (size_t)i * V;
    f4*          phirow  = (f4*)out_phi + (size_t)i * V;
    float*       attnrow = out_attn + (size_t)i * V;

    // ---- pass 1: phi + ea = a*exp(leaky(logit)) (max-shift-invariant), s, t ----
    float ea[NITER];
    float s = 0.f, t = 0.f;
#pragma unroll
    for (int k = 0; k < NITER; ++k) {
        int j = tid + k * 256;
        float a = __builtin_nontemporal_load(adjrow + j);
        f4 na = nd4[2 * j];
        f4 nb = nd4[2 * j + 1];
        float dx = pix - na.x, dy = piy - na.y;
        float dist = sqrtf(dx * dx + dy * dy);
        float dvx = vix - na.z, dvy = viy - na.w;
        float vdiff = sqrtf(dvx * dvx + dvy * dvy);
        float al = fminf(1.f, fmaxf(-1.f, dix * nb.x + diy * nb.y));
        int gj = __float_as_int(nb.w);
        float conf = (gi >= 0 && gj >= 0) ? conflict[(size_t)gi * GSZ + gj] : 0.f;

        f4 ph;
        ph.x = dist; ph.y = vdiff; ph.z = al; ph.w = conf;
        __builtin_nontemporal_store(ph, phirow + j);

        float lg = li_i + nb.z + dist * w0 + vdiff * w1 + al * w2 + conf * w3;
        lg = (lg >= 0.f) ? lg : SLOPE * lg;
        // suppressed entries contribute exactly 0 (exp(lg-1e9)==0 in fp32)
        float e = (a > 0.f) ? __expf(fminf(lg, 80.f)) : 0.f;
        ea[k] = e * a;
        s += e;
        t += e * a;
    }
#pragma unroll
    for (int off = 32; off; off >>= 1) {
        s += __shfl_xor(s, off);
        t += __shfl_xor(t, off);
    }
    if ((tid & 63) == 0) { red[tid >> 6] = s; red[4 + (tid >> 6)] = t; }
    __syncthreads();
    s = red[0] + red[1] + red[2] + red[3];
    t = red[4] + red[5] + red[6] + red[7];
    const float denom = t + EPS * s;
    const float dinv  = (denom > 0.f) ? 1.f / denom : 0.f;

    // ---- pass 2: attn row + attended accumulation (no adj re-read) ----
    float acc[H];
#pragma unroll
    for (int c = 0; c < H; ++c) acc[c] = 0.f;
    const f4* h4 = (const f4*)h;
#pragma unroll
    for (int k = 0; k < NITER; ++k) {
        int j = tid + k * 256;
        float w = ea[k] * dinv;
        __builtin_nontemporal_store(w, attnrow + j);
#pragma unroll
        for (int c4 = 0; c4 < H / 4; ++c4) {
            f4 hv = h4[j * (H / 4) + c4];
            acc[c4 * 4 + 0] += w * hv.x;
            acc[c4 * 4 + 1] += w * hv.y;
            acc[c4 * 4 + 2] += w * hv.z;
            acc[c4 * 4 + 3] += w * hv.w;
        }
    }
#pragma unroll
    for (int c = 0; c < H; ++c)
#pragma unroll
        for (int off = 32; off; off >>= 1) acc[c] += __shfl_xor(acc[c], off);

    if ((tid & 63) == 0) {
        int wv = tid >> 6;
#pragma unroll
        for (int c = 0; c < H; ++c) atile[wv * H + c] = acc[c];
    }
    __syncthreads();
    if (tid < H) {
        out_att[(size_t)i * H + tid] =
            atile[tid] + atile[H + tid] + atile[2 * H + tid] + atile[3 * H + tid];
    }
}

extern "C" void kernel_launch(void* const* d_in, const int* in_sizes, int n_in,
                              void* d_out, int out_size, void* d_ws, size_t ws_size,
                              hipStream_t stream) {
    const float* feat     = (const float*)d_in[0];
    const float* adj      = (const float*)d_in[1];
    const float* pos      = (const float*)d_in[2];
    const float* vel      = (const float*)d_in[3];
    const int*   types    = (const int*)  d_in[4];
    const int*   nped     = (const int*)  d_in[5];
    const float* conflict = (const float*)d_in[6];
    const float* Wp       = (const float*)d_in[7];
    const float* wscore   = (const float*)d_in[8];

    float* out = (float*)d_out;
    float* out_att  = out;                                   // [V,H]
    float* out_attn = out + (size_t)V * H;                   // [V,V]
    float* out_phi  = out + (size_t)V * H + (size_t)V * V;   // [V,V,4]

    float* ws = (float*)d_ws;
    float* h  = ws;                        // V*H
    float* li = h + (size_t)V * H;         // V
    float* nd = li + V;                    // V*8

    prep_kernel<<<dim3(V / 256), dim3(256), 0, stream>>>(
        feat, pos, vel, types, nped, Wp, wscore, h, li, nd);

    row_kernel<<<dim3(V), dim3(256), 0, stream>>>(
        adj, conflict, wscore, h, li, nd, out_att, out_attn, out_phi);
}

// Round 5
// 157.998 us; speedup vs baseline: 3.0789x; 1.5205x over previous
//
#include <hip/hip_runtime.h>

#define V 4096
#define F 64
#define H 16
#define GSZ 1024
#define EPS 1e-8f
#define SLOPE 0.2f
#define NITER (V / 256)   // 16 columns per thread

typedef float f4 __attribute__((ext_vector_type(4)));

// ---------------- Kernel A: per-node precompute + packing ----------------
// na[j] = {px, py, vx, vy}
// nb[j] = {dirx, diry, lj, bitcast(gc)}
// hg[c4*V + j] = {h[j][4c4], h[j][4c4+1], h[j][4c4+2], h[j][4c4+3]}
__global__ __launch_bounds__(256) void prep_kernel(
    const float* __restrict__ feat,      // [V,F]
    const float* __restrict__ pos,       // [V,2]
    const float* __restrict__ vel,       // [V,2]
    const int*   __restrict__ types,     // [V]
    const int*   __restrict__ nped,      // [1]
    const float* __restrict__ Wp,        // [F,H]
    const float* __restrict__ wscore,    // [2H+4]
    f4*    __restrict__ hg,              // [H/4][V]
    float* __restrict__ li,              // [V]
    f4*    __restrict__ na,              // [V]
    f4*    __restrict__ nb)              // [V]
{
    int i = blockIdx.x * blockDim.x + threadIdx.x;
    if (i >= V) return;

    float acc[H];
#pragma unroll
    for (int c = 0; c < H; ++c) acc[c] = 0.f;
    for (int f = 0; f < F; ++f) {
        float x = feat[i * F + f];
#pragma unroll
        for (int c = 0; c < H; ++c) acc[c] += x * Wp[f * H + c];
    }
    float sli = 0.f, slj = 0.f;
#pragma unroll
    for (int c = 0; c < H; ++c) {
        sli += acc[c] * wscore[c];
        slj += acc[c] * wscore[H + c];
    }
#pragma unroll
    for (int c4 = 0; c4 < H / 4; ++c4) {
        f4 hv;
        hv.x = acc[c4 * 4 + 0];
        hv.y = acc[c4 * 4 + 1];
        hv.z = acc[c4 * 4 + 2];
        hv.w = acc[c4 * 4 + 3];
        hg[c4 * V + i] = hv;
    }
    li[i] = sli;

    float vx = vel[i * 2], vy = vel[i * 2 + 1];
    float inv = 1.f / (sqrtf(vx * vx + vy * vy) + EPS);
    int P = nped[0];
    int g = i - P;
    int gc = (types[i] == 1 && g >= 0 && g < GSZ) ? g : -1;

    f4 A, B;
    A.x = pos[i * 2]; A.y = pos[i * 2 + 1]; A.z = vx; A.w = vy;
    B.x = vx * inv;   B.y = vy * inv;       B.z = slj; B.w = __int_as_float(gc);
    na[i] = A;
    nb[i] = B;
}

// ---------------- Kernel B: one block per row ----------------
__global__ __launch_bounds__(256, 8) void row_kernel(
    const float* __restrict__ adj,       // [V,V]
    const float* __restrict__ conflict,  // [G,G]
    const float* __restrict__ wscore,    // [2H+4]
    const f4*    __restrict__ hg,        // [H/4][V]
    const float* __restrict__ li,        // [V]
    const f4*    __restrict__ na,        // [V]
    const f4*    __restrict__ nb,        // [V]
    float* __restrict__ out_att,         // [V,H]
    float* __restrict__ out_attn,        // [V,V]
    float* __restrict__ out_phi)         // [V,V,4]
{
    const int i   = blockIdx.x;
    const int tid = threadIdx.x;

    __shared__ float red[8];
    __shared__ float atile[4 * H];

    const f4 ra = na[i];
    const f4 rb = nb[i];
    const float pix = ra.x, piy = ra.y, vix = ra.z, viy = ra.w;
    const float dix = rb.x, diy = rb.y;
    const int   gi  = __float_as_int(rb.w);
    const float li_i = li[i];
    const float w0 = wscore[2 * H + 0];
    const float w1 = wscore[2 * H + 1];
    const float w2 = wscore[2 * H + 2];
    const float w3 = wscore[2 * H + 3];

    const float* adjrow  = adj + (size_t)i * V;
    f4*          phirow  = (f4*)out_phi + (size_t)i * V;
    float*       attnrow = out_attn + (size_t)i * V;

    // ---- pass 1: phi + ea = a*exp(leaky(logit)) (max-shift-invariant), s, t ----
    float ea[NITER];
    float s = 0.f, t = 0.f;
#pragma unroll
    for (int k = 0; k < NITER; ++k) {
        int j = tid + k * 256;
        float a = __builtin_nontemporal_load(adjrow + j);
        f4 A = na[j];
        f4 B = nb[j];
        float dx = pix - A.x, dy = piy - A.y;
        float dist = sqrtf(dx * dx + dy * dy);
        float dvx = vix - A.z, dvy = viy - A.w;
        float vdiff = sqrtf(dvx * dvx + dvy * dvy);
        float al = fminf(1.f, fmaxf(-1.f, dix * B.x + diy * B.y));
        int gj = __float_as_int(B.w);
        float conf = (gi >= 0 && gj >= 0) ? conflict[(size_t)gi * GSZ + gj] : 0.f;

        f4 ph;
        ph.x = dist; ph.y = vdiff; ph.z = al; ph.w = conf;
        __builtin_nontemporal_store(ph, phirow + j);

        float lg = li_i + B.z + dist * w0 + vdiff * w1 + al * w2 + conf * w3;
        lg = (lg >= 0.f) ? lg : SLOPE * lg;
        // suppressed entries contribute exactly 0 (exp(lg-1e9)==0 in fp32)
        float e = (a > 0.f) ? __expf(fminf(lg, 80.f)) : 0.f;
        ea[k] = e * a;
        s += e;
        t += e * a;
    }
#pragma unroll
    for (int off = 32; off; off >>= 1) {
        s += __shfl_xor(s, off);
        t += __shfl_xor(t, off);
    }
    if ((tid & 63) == 0) { red[tid >> 6] = s; red[4 + (tid >> 6)] = t; }
    __syncthreads();
    s = red[0] + red[1] + red[2] + red[3];
    t = red[4] + red[5] + red[6] + red[7];
    const float denom = t + EPS * s;
    const float dinv  = (denom > 0.f) ? 1.f / denom : 0.f;

    // ---- pass 2: attn row + attended accumulation (c4-major h, coalesced) ----
    float acc[H];
#pragma unroll
    for (int c = 0; c < H; ++c) acc[c] = 0.f;
#pragma unroll
    for (int k = 0; k < NITER; ++k) {
        int j = tid + k * 256;
        float w = ea[k] * dinv;
        __builtin_nontemporal_store(w, attnrow + j);
#pragma unroll
        for (int c4 = 0; c4 < H / 4; ++c4) {
            f4 hv = hg[c4 * V + j];   // lane-contiguous 16B
            acc[c4 * 4 + 0] += w * hv.x;
            acc[c4 * 4 + 1] += w * hv.y;
            acc[c4 * 4 + 2] += w * hv.z;
            acc[c4 * 4 + 3] += w * hv.w;
        }
    }
#pragma unroll
    for (int c = 0; c < H; ++c)
#pragma unroll
        for (int off = 32; off; off >>= 1) acc[c] += __shfl_xor(acc[c], off);

    if ((tid & 63) == 0) {
        int wv = tid >> 6;
#pragma unroll
        for (int c = 0; c < H; ++c) atile[wv * H + c] = acc[c];
    }
    __syncthreads();
    if (tid < H) {
        out_att[(size_t)i * H + tid] =
            atile[tid] + atile[H + tid] + atile[2 * H + tid] + atile[3 * H + tid];
    }
}

extern "C" void kernel_launch(void* const* d_in, const int* in_sizes, int n_in,
                              void* d_out, int out_size, void* d_ws, size_t ws_size,
                              hipStream_t stream) {
    const float* feat     = (const float*)d_in[0];
    const float* adj      = (const float*)d_in[1];
    const float* pos      = (const float*)d_in[2];
    const float* vel      = (const float*)d_in[3];
    const int*   types    = (const int*)  d_in[4];
    const int*   nped     = (const int*)  d_in[5];
    const float* conflict = (const float*)d_in[6];
    const float* Wp       = (const float*)d_in[7];
    const float* wscore   = (const float*)d_in[8];

    float* out = (float*)d_out;
    float* out_att  = out;                                   // [V,H]
    float* out_attn = out + (size_t)V * H;                   // [V,V]
    float* out_phi  = out + (size_t)V * H + (size_t)V * V;   // [V,V,4]

    // workspace layout
    float* ws = (float*)d_ws;
    f4*    hg = (f4*)ws;                         // (H/4)*V f4  = 256 KB
    float* li = ws + (size_t)V * H;              // V floats
    f4*    na = (f4*)(li + V);                   // V f4 = 64 KB
    f4*    nb = na + V;                          // V f4 = 64 KB

    prep_kernel<<<dim3(V / 256), dim3(256), 0, stream>>>(
        feat, pos, vel, types, nped, Wp, wscore, hg, li, na, nb);

    row_kernel<<<dim3(V), dim3(256), 0, stream>>>(
        adj, conflict, wscore, hg, li, na, nb, out_att, out_attn, out_phi);
}

// Round 6
// 92.844 us; speedup vs baseline: 5.2396x; 1.7018x over previous
//
#include <hip/hip_runtime.h>

#define V 4096
#define F 64
#define H 16
#define GSZ 1024
#define EPS 1e-8f
#define SLOPE 0.2f
#define NITER (V / 256)   // 16 columns per thread

typedef float f4 __attribute__((ext_vector_type(4)));

// ---------------- Kernel A: per-node precompute + packing ----------------
// na[j] = {px, py, vx, vy}
// nb[j] = {dirx, diry, lj, bitcast(gc)}
// hg[c4*V + j] = {h[j][4c4], h[j][4c4+1], h[j][4c4+2], h[j][4c4+3]}
__global__ __launch_bounds__(256) void prep_kernel(
    const float* __restrict__ feat,      // [V,F]
    const float* __restrict__ pos,       // [V,2]
    const float* __restrict__ vel,       // [V,2]
    const int*   __restrict__ types,     // [V]
    const int*   __restrict__ nped,      // [1]
    const float* __restrict__ Wp,        // [F,H]
    const float* __restrict__ wscore,    // [2H+4]
    f4*    __restrict__ hg,              // [H/4][V]
    float* __restrict__ li,              // [V]
    f4*    __restrict__ na,              // [V]
    f4*    __restrict__ nb)              // [V]
{
    int i = blockIdx.x * blockDim.x + threadIdx.x;
    if (i >= V) return;

    float acc[H];
#pragma unroll
    for (int c = 0; c < H; ++c) acc[c] = 0.f;
    for (int f = 0; f < F; ++f) {
        float x = feat[i * F + f];
#pragma unroll
        for (int c = 0; c < H; ++c) acc[c] += x * Wp[f * H + c];
    }
    float sli = 0.f, slj = 0.f;
#pragma unroll
    for (int c = 0; c < H; ++c) {
        sli += acc[c] * wscore[c];
        slj += acc[c] * wscore[H + c];
    }
#pragma unroll
    for (int c4 = 0; c4 < H / 4; ++c4) {
        f4 hv;
        hv.x = acc[c4 * 4 + 0];
        hv.y = acc[c4 * 4 + 1];
        hv.z = acc[c4 * 4 + 2];
        hv.w = acc[c4 * 4 + 3];
        hg[c4 * V + i] = hv;
    }
    li[i] = sli;

    float vx = vel[i * 2], vy = vel[i * 2 + 1];
    float inv = 1.f / (sqrtf(vx * vx + vy * vy) + EPS);
    int P = nped[0];
    int g = i - P;
    int gc = (types[i] == 1 && g >= 0 && g < GSZ) ? g : -1;

    f4 A, B;
    A.x = pos[i * 2]; A.y = pos[i * 2 + 1]; A.z = vx; A.w = vy;
    B.x = vx * inv;   B.y = vy * inv;       B.z = slj; B.w = __int_as_float(gc);
    na[i] = A;
    nb[i] = B;
}

// ---------------- Kernel B: one block per row ----------------
__global__ __launch_bounds__(256, 8) void row_kernel(
    const float* __restrict__ adj,       // [V,V]
    const float* __restrict__ conflict,  // [G,G]
    const float* __restrict__ wscore,    // [2H+4]
    const f4*    __restrict__ hg,        // [H/4][V]
    const float* __restrict__ li,        // [V]
    const f4*    __restrict__ na,        // [V]
    const f4*    __restrict__ nb,        // [V]
    float* __restrict__ out_att,         // [V,H]
    float* __restrict__ out_attn,        // [V,V]
    float* __restrict__ out_phi)         // [V,V,4]
{
    const int i   = blockIdx.x;
    const int tid = threadIdx.x;

    __shared__ float red[8];
    __shared__ float atile[4 * H];

    const f4 ra = na[i];
    const f4 rb = nb[i];
    const float pix = ra.x, piy = ra.y, vix = ra.z, viy = ra.w;
    const float dix = rb.x, diy = rb.y;
    const int   gi  = __float_as_int(rb.w);
    const float li_i = li[i];
    const float w0 = wscore[2 * H + 0];
    const float w1 = wscore[2 * H + 1];
    const float w2 = wscore[2 * H + 2];
    const float w3 = wscore[2 * H + 3];

    const float* adjrow  = adj + (size_t)i * V;
    f4*          phirow  = (f4*)out_phi + (size_t)i * V;
    float*       attnrow = out_attn + (size_t)i * V;

    // ---- pass 1: phi + ea = a*exp(leaky(logit)) (max-shift-invariant), s, t ----
    float ea[NITER];
    float s = 0.f, t = 0.f;
#pragma unroll
    for (int k = 0; k < NITER; ++k) {
        int j = tid + k * 256;
        float a = adjrow[j];              // plain load: keep adjacency L3-warm
        f4 A = na[j];
        f4 B = nb[j];
        float dx = pix - A.x, dy = piy - A.y;
        float dist = sqrtf(dx * dx + dy * dy);
        float dvx = vix - A.z, dvy = viy - A.w;
        float vdiff = sqrtf(dvx * dvx + dvy * dvy);
        float al = fminf(1.f, fmaxf(-1.f, dix * B.x + diy * B.y));
        int gj = __float_as_int(B.w);
        float conf = (gi >= 0 && gj >= 0) ? conflict[(size_t)gi * GSZ + gj] : 0.f;

        f4 ph;
        ph.x = dist; ph.y = vdiff; ph.z = al; ph.w = conf;
        __builtin_nontemporal_store(ph, phirow + j);

        float lg = li_i + B.z + dist * w0 + vdiff * w1 + al * w2 + conf * w3;
        lg = (lg >= 0.f) ? lg : SLOPE * lg;
        // suppressed entries contribute exactly 0 (exp(lg-1e9)==0 in fp32)
        float e = (a > 0.f) ? __expf(fminf(lg, 80.f)) : 0.f;
        ea[k] = e * a;
        s += e;
        t += e * a;
    }
#pragma unroll
    for (int off = 32; off; off >>= 1) {
        s += __shfl_xor(s, off);
        t += __shfl_xor(t, off);
    }
    if ((tid & 63) == 0) { red[tid >> 6] = s; red[4 + (tid >> 6)] = t; }
    __syncthreads();
    s = red[0] + red[1] + red[2] + red[3];
    t = red[4] + red[5] + red[6] + red[7];
    const float denom = t + EPS * s;
    const float dinv  = (denom > 0.f) ? 1.f / denom : 0.f;

    // ---- pass 2: attn row + attended accumulation (c4-major h, coalesced) ----
    float acc[H];
#pragma unroll
    for (int c = 0; c < H; ++c) acc[c] = 0.f;
#pragma unroll
    for (int k = 0; k < NITER; ++k) {
        int j = tid + k * 256;
        float w = ea[k] * dinv;
        __builtin_nontemporal_store(w, attnrow + j);
#pragma unroll
        for (int c4 = 0; c4 < H / 4; ++c4) {
            f4 hv = hg[c4 * V + j];   // lane-contiguous 16B
            acc[c4 * 4 + 0] += w * hv.x;
            acc[c4 * 4 + 1] += w * hv.y;
            acc[c4 * 4 + 2] += w * hv.z;
            acc[c4 * 4 + 3] += w * hv.w;
        }
    }
#pragma unroll
    for (int c = 0; c < H; ++c)
#pragma unroll
        for (int off = 32; off; off >>= 1) acc[c] += __shfl_xor(acc[c], off);

    if ((tid & 63) == 0) {
        int wv = tid >> 6;
#pragma unroll
        for (int c = 0; c < H; ++c) atile[wv * H + c] = acc[c];
    }
    __syncthreads();
    if (tid < H) {
        out_att[(size_t)i * H + tid] =
            atile[tid] + atile[H + tid] + atile[2 * H + tid] + atile[3 * H + tid];
    }
}

extern "C" void kernel_launch(void* const* d_in, const int* in_sizes, int n_in,
                              void* d_out, int out_size, void* d_ws, size_t ws_size,
                              hipStream_t stream) {
    const float* feat     = (const float*)d_in[0];
    const float* adj      = (const float*)d_in[1];
    const float* pos      = (const float*)d_in[2];
    const float* vel      = (const float*)d_in[3];
    const int*   types    = (const int*)  d_in[4];
    const int*   nped     = (const int*)  d_in[5];
    const float* conflict = (const float*)d_in[6];
    const float* Wp       = (const float*)d_in[7];
    const float* wscore   = (const float*)d_in[8];

    float* out = (float*)d_out;
    float* out_att  = out;                                   // [V,H]
    float* out_attn = out + (size_t)V * H;                   // [V,V]
    float* out_phi  = out + (size_t)V * H + (size_t)V * V;   // [V,V,4]

    // workspace layout
    float* ws = (float*)d_ws;
    f4*    hg = (f4*)ws;                         // (H/4)*V f4  = 256 KB
    float* li = ws + (size_t)V * H;              // V floats
    f4*    na = (f4*)(li + V);                   // V f4 = 64 KB
    f4*    nb = na + V;                          // V f4 = 64 KB

    prep_kernel<<<dim3(V / 256), dim3(256), 0, stream>>>(
        feat, pos, vel, types, nped, Wp, wscore, hg, li, na, nb);

    row_kernel<<<dim3(V), dim3(256), 0, stream>>>(
        adj, conflict, wscore, hg, li, na, nb, out_att, out_attn, out_phi);
}